// Round 2
// 368.288 us; speedup vs baseline: 1.0070x; 1.0070x over previous
//
#include <hip/hip_runtime.h>

typedef __bf16 bf16;
typedef __bf16 bf16x8 __attribute__((ext_vector_type(8)));
typedef float f32x4 __attribute__((ext_vector_type(4)));

#define BB 4
#define SS 2048
#define HH 16
#define DD 1024
#define DK 64
#define MTOT (BB * SS)   // 8192

#define C1 0.18033688f    // 0.125 * log2(e)
#define C2 -11.5415603f   // -8 * log2(e)

// async global->LDS, 16B per lane. LDS dest is WAVE-UNIFORM base; HW scatters
// lane i to base + i*16.
__device__ __forceinline__ void gl_lds16(const bf16* g, bf16* l)
{
    __builtin_amdgcn_global_load_lds(
        (const __attribute__((address_space(1))) unsigned int*)g,
        (__attribute__((address_space(3))) unsigned int*)l, 16, 0, 0);
}

// ---------------------------------------------------------------------------
// fp32 -> bf16 bulk converts, one dispatch. z 0..2: X inputs; z=3: 4 weights.
// ---------------------------------------------------------------------------
__global__ __launch_bounds__(256) void conv_kernel(
    const float* __restrict__ q, const float* __restrict__ k,
    const float* __restrict__ v,
    const float* __restrict__ wq, const float* __restrict__ wk,
    const float* __restrict__ wv, const float* __restrict__ wp,
    bf16* __restrict__ xdst, bf16* __restrict__ wdst)
{
    const float* src; bf16* d; size_t i;
    if (blockIdx.z < 3) {
        src = (blockIdx.z == 0) ? q : (blockIdx.z == 1) ? k : v;
        d = xdst + (size_t)blockIdx.z * ((size_t)MTOT * DD);
        i = ((size_t)blockIdx.x * 256 + threadIdx.x) * 8;
    } else {
        if (blockIdx.x >= 2048) return;
        const int wsel = blockIdx.x >> 9;
        src = (wsel == 0) ? wq : (wsel == 1) ? wk : (wsel == 2) ? wv : wp;
        d = wdst + (size_t)wsel * ((size_t)DD * DD);
        i = ((size_t)(blockIdx.x & 511) * 256 + threadIdx.x) * 8;
    }
    const float4 v0 = *(const float4*)(src + i);
    const float4 v1 = *(const float4*)(src + i + 4);
    bf16x8 r = { (bf16)v0.x, (bf16)v0.y, (bf16)v0.z, (bf16)v0.w,
                 (bf16)v1.x, (bf16)v1.y, (bf16)v1.z, (bf16)v1.w };
    *(bf16x8*)(d + i) = r;
}

// ---------------------------------------------------------------------------
// QKV GEMM, 8-phase 256x256 schedule (m201 template, plain HIP):
//   BK=64, 512 threads = 8 waves (2M x 4N), per-wave C = 128x64.
//   LDS: 2 buffers x (A 32KB + B 32KB) = 128 KB.
//   Tile layout: [kc(2)][row(256)][4 chunks x 16B], chunk ^= (row>>1)&3
//   (conflict-free ds_read_b128; staged via linear global_load_lds with
//   inverse-swizzled global source -- both-sides-or-neither rule).
//   Per K-tile: 4 phases {ds_read quadrant; barrier; lgkmcnt(0);
//   setprio(1)+16 MFMA+setprio(0); stage 1 kc-half of tile T+2; barrier},
//   boundary s_waitcnt vmcnt(8) (counted, never 0 in steady state).
// One dispatch, z selects {Q,K,V}. z<2: scatter [b,h,s,dk]. z==2: V^T
// [b,h,dk,s] via per-wave LDS transpose after the loop.
// ---------------------------------------------------------------------------
template<int KC, int NH>
__device__ __forceinline__ void qphase(
    const bf16* __restrict__ sb, int wm, int wn, int lr, int swz8,
    bf16x8 a[8], f32x4 acc[8][4],
    const bf16* __restrict__ ssrc, bf16* __restrict__ sdst, bool doStage)
{
    if constexpr (NH == 0) {
        #pragma unroll
        for (int i = 0; i < 8; ++i)
            a[i] = *(const bf16x8*)&sb[KC * 8192 + (wm * 128 + i * 16 + lr) * 32 + swz8];
    }
    bf16x8 b0 = *(const bf16x8*)&sb[16384 + KC * 8192 + (wn * 64 + (NH * 2 + 0) * 16 + lr) * 32 + swz8];
    bf16x8 b1 = *(const bf16x8*)&sb[16384 + KC * 8192 + (wn * 64 + (NH * 2 + 1) * 16 + lr) * 32 + swz8];
    __builtin_amdgcn_s_barrier();
    asm volatile("s_waitcnt lgkmcnt(0)" ::: "memory");
    __builtin_amdgcn_s_setprio(1);
    #pragma unroll
    for (int i = 0; i < 8; ++i) {
        acc[i][NH * 2 + 0] = __builtin_amdgcn_mfma_f32_16x16x32_bf16(
                                 a[i], b0, acc[i][NH * 2 + 0], 0, 0, 0);
        acc[i][NH * 2 + 1] = __builtin_amdgcn_mfma_f32_16x16x32_bf16(
                                 a[i], b1, acc[i][NH * 2 + 1], 0, 0, 0);
    }
    __builtin_amdgcn_s_setprio(0);
    // stage AFTER the MFMA cluster: every wave's reads of the region being
    // overwritten were issued pre-barrier and waited via lgkmcnt(0) before
    // MFMAs; the >=200cy load-return latency lands well after.
    if (doStage) {
        gl_lds16(ssrc, sdst);
        gl_lds16(ssrc + (size_t)128 * DD, sdst + 4096);
    }
}

__global__ __launch_bounds__(512, 2) void gemm_qkv(
    const bf16* __restrict__ x0, const bf16* __restrict__ x1,
    const bf16* __restrict__ x2, const bf16* __restrict__ w0,
    const bf16* __restrict__ w1, const bf16* __restrict__ w2,
    const float* __restrict__ bias0, const float* __restrict__ bias1,
    const float* __restrict__ bias2,
    bf16* __restrict__ o0, bf16* __restrict__ o1, bf16* __restrict__ o2)
{
    __shared__ __align__(16) bf16 smem[2 * 32768];   // 128 KB

    const int z = blockIdx.z;
    const bf16* A = (z == 0) ? x0 : (z == 1) ? x1 : x2;
    const bf16* W = (z == 0) ? w0 : (z == 1) ? w1 : w2;
    const float* bias = (z == 0) ? bias0 : (z == 1) ? bias1 : bias2;
    bf16* out = (z == 0) ? o0 : (z == 1) ? o1 : o2;

    const int tid  = threadIdx.x;
    const int w    = tid >> 6;
    const int lane = tid & 63;
    const int quad = lane >> 4;
    const int lr   = lane & 15;
    const int wm   = w >> 2;       // 2 m-waves of 128 rows
    const int wn   = w & 3;        // 4 n-waves of 64 cols

    const int m_base = blockIdx.y * 256;
    const int n_base = blockIdx.x * 256;
    const int swz8 = (quad ^ ((lr >> 1) & 3)) * 8;

    // staging: linear LDS dest; source column pre-swizzled (inverse of read swz)
    const int c0 = ((tid & 3) ^ ((tid >> 3) & 3)) * 8;
    const bf16* srcA = A + (size_t)(m_base + (tid >> 2)) * DD + c0;
    const bf16* srcB = W + (size_t)(n_base + (tid >> 2)) * DD + c0;

    f32x4 acc[8][4];
    #pragma unroll
    for (int i = 0; i < 8; ++i)
        #pragma unroll
        for (int j = 0; j < 4; ++j)
            acc[i][j] = (f32x4){0.f, 0.f, 0.f, 0.f};
    bf16x8 a[8];

    // prologue: stage K-tiles 0 and 1 (8 loads/thread each)
    #pragma unroll
    for (int t = 0; t < 2; ++t) {
        bf16* db = smem + t * 32768;
        #pragma unroll
        for (int kc = 0; kc < 2; ++kc) {
            const bf16* sA = srcA + t * 64 + kc * 32;
            const bf16* sB = srcB + t * 64 + kc * 32;
            gl_lds16(sA,                      db + kc * 8192 + w * 512);
            gl_lds16(sA + (size_t)128 * DD,   db + kc * 8192 + 4096 + w * 512);
            gl_lds16(sB,                      db + 16384 + kc * 8192 + w * 512);
            gl_lds16(sB + (size_t)128 * DD,   db + 16384 + kc * 8192 + 4096 + w * 512);
        }
    }
    asm volatile("s_waitcnt vmcnt(8)" ::: "memory");   // tile 0 landed; tile 1 in flight
    __builtin_amdgcn_s_barrier();

    #pragma unroll 2
    for (int T = 0; T < 16; ++T) {
        const bf16* sb = smem + (T & 1) * 32768;
        bf16* db = smem + (T & 1) * 32768;        // tile T+2 shares parity with T
        const bool st = (T + 2 < 16);
        const int tn = st ? (T + 2) : 0;
        const bf16* sA = srcA + tn * 64;
        const bf16* sB = srcB + tn * 64;

        qphase<0, 0>(sb, wm, wn, lr, swz8, a, acc, sA,      db + w * 512,                 st);
        __builtin_amdgcn_s_barrier();
        qphase<0, 1>(sb, wm, wn, lr, swz8, a, acc, sB,      db + 16384 + w * 512,         st);
        __builtin_amdgcn_s_barrier();
        qphase<1, 0>(sb, wm, wn, lr, swz8, a, acc, sA + 32, db + 8192 + w * 512,          st);
        __builtin_amdgcn_s_barrier();
        qphase<1, 1>(sb, wm, wn, lr, swz8, a, acc, sB + 32, db + 16384 + 8192 + w * 512,  st);
        if (st) asm volatile("s_waitcnt vmcnt(8)" ::: "memory");  // T+1 landed, T+2 flying
        else    asm volatile("s_waitcnt vmcnt(0)" ::: "memory");  // tail drain
        __builtin_amdgcn_s_barrier();
    }

    if (z == 2) {
        // V^T epilogue: per-wave 16x128 transpose buffer (stride 136), 4 rounds.
        bf16* e = smem + w * 2176;
        const int hh = (n_base + wn * 64) >> 6;
        const int mg = m_base + wm * 128;
        const int b  = mg >> 11;
        const int s0 = mg & (SS - 1);
        #pragma unroll
        for (int j = 0; j < 4; ++j) {
            const float bb = bias[n_base + wn * 64 + j * 16 + lr];
            #pragma unroll
            for (int i = 0; i < 8; ++i)
                #pragma unroll
                for (int r = 0; r < 4; ++r)
                    e[lr * 136 + i * 16 + quad * 4 + r] = (bf16)(acc[i][j][r] + bb);
            #pragma unroll
            for (int p = 0; p < 4; ++p) {
                const int nn = p * 4 + quad;
                const int mm = lr * 8;
                const bf16x8 vv = *(const bf16x8*)&e[nn * 136 + mm];
                const int dk = j * 16 + nn;
                *(bf16x8*)(out + ((size_t)(b * HH + hh) * DK + dk) * SS + s0 + mm) = vv;
            }
        }
    } else {
        #pragma unroll
        for (int j = 0; j < 4; ++j) {
            const int n  = n_base + wn * 64 + j * 16 + lr;
            const float bb = bias[n];
            const int hh = n >> 6;
            const int dk = n & (DK - 1);
            #pragma unroll
            for (int i = 0; i < 8; ++i)
                #pragma unroll
                for (int r = 0; r < 4; ++r) {
                    const int m = m_base + wm * 128 + i * 16 + quad * 4 + r;
                    const int bi = m >> 11, s = m & (SS - 1);
                    out[(((size_t)bi * HH + hh) * SS + s) * DK + dk]
                        = (bf16)(acc[i][j][r] + bb);
                }
        }
    }
}

// ---------------------------------------------------------------------------
// Output projection GEMM: 128m x 64n tiles (grid 16x64 = 1024 blocks -> 4/CU).
// Each wave: 32m x 64n. fp32 output.
// ---------------------------------------------------------------------------
__global__ __launch_bounds__(256) void gemm_out(
    const bf16* __restrict__ A, const bf16* __restrict__ W,
    const float* __restrict__ bias, float* __restrict__ out)
{
    __shared__ __align__(16) bf16 As[128 * 32];
    __shared__ __align__(16) bf16 Bs[64 * 32];

    const int tid  = threadIdx.x;
    const int wave = tid >> 6;
    const int lane = tid & 63;
    const int quad = lane >> 4;
    const int lr   = lane & 15;

    const int m_base = blockIdx.y * 128;
    const int n_base = blockIdx.x * 64;
    const int srow = lane >> 2;
    const int scol = (lane & 3) * 8;

    f32x4 acc[2][4];
    #pragma unroll
    for (int i = 0; i < 2; ++i)
        #pragma unroll
        for (int j = 0; j < 4; ++j)
            acc[i][j] = (f32x4){0.f, 0.f, 0.f, 0.f};

    for (int k0 = 0; k0 < DD; k0 += 32) {
        #pragma unroll
        for (int seg = wave; seg < 12; seg += 4) {
            if (seg < 8)
                gl_lds16(A + (size_t)(m_base + seg * 16 + srow) * DD + k0 + scol,
                         As + seg * 512);
            else
                gl_lds16(W + (size_t)(n_base + (seg - 8) * 16 + srow) * DD + k0 + scol,
                         Bs + (seg - 8) * 512);
        }
        __syncthreads();

        bf16x8 af[2], bfr[4];
        #pragma unroll
        for (int i = 0; i < 2; ++i)
            af[i] = *(const bf16x8*)&As[(wave * 32 + i * 16 + lr) * 32 + quad * 8];
        #pragma unroll
        for (int j = 0; j < 4; ++j)
            bfr[j] = *(const bf16x8*)&Bs[(j * 16 + lr) * 32 + quad * 8];

        #pragma unroll
        for (int i = 0; i < 2; ++i)
            #pragma unroll
            for (int j = 0; j < 4; ++j)
                acc[i][j] = __builtin_amdgcn_mfma_f32_16x16x32_bf16(
                                af[i], bfr[j], acc[i][j], 0, 0, 0);
        __syncthreads();
    }

    #pragma unroll
    for (int j = 0; j < 4; ++j) {
        const int n = n_base + j * 16 + lr;
        const float bb = bias[n];
        #pragma unroll
        for (int i = 0; i < 2; ++i)
            #pragma unroll
            for (int r = 0; r < 4; ++r) {
                const int m = m_base + wave * 32 + i * 16 + quad * 4 + r;
                out[(size_t)m * DD + n] = acc[i][j][r] + bb;
            }
    }
}

// ---------------------------------------------------------------------------
// MFMA flash attention v4: 4-wave blocks; wave w owns 32 Q rows
// (m0 = qg*128 + w*32); K/V 32-wide tiles staged ONCE per block into
// double-buffered LDS (XOR-swizzled 16B chunks -> uniform-bank b128 reads).
// Fixed-max softmax p = exp2(s*C1 + C2). Row-sum l via MFMA ones-fragment.
// ---------------------------------------------------------------------------
template <bool DIAG>
__device__ __forceinline__ void attn_tile4(
    int quad, int lr, const bf16* __restrict__ Kc, const bf16* __restrict__ Vc,
    bf16* __restrict__ pb, const bf16x8 aq[2][2], const bf16x8& ones,
    f32x4 acc[2][4], f32x4 acc_l[2])
{
    // K frags: logical (row=kvh*16+lr, cc=kc*4+quad), phys chunk row*8 + (cc^(row&7))
    bf16x8 kb[2][2];
    #pragma unroll
    for (int kvh = 0; kvh < 2; ++kvh)
        #pragma unroll
        for (int kc = 0; kc < 2; ++kc)
            kb[kvh][kc] = *(const bf16x8*)&Kc[
                ((kvh * 16 + lr) * 8 + ((kc * 4 + quad) ^ (lr & 7))) * 8];
    // V frags: logical (row=c*16+lr, cc=quad), phys chunk row*4 + (cc^((row>>1)&3))
    bf16x8 vb[4];
    #pragma unroll
    for (int c = 0; c < 4; ++c)
        vb[c] = *(const bf16x8*)&Vc[
            ((c * 16 + lr) * 4 + (quad ^ ((lr >> 1) & 3))) * 8];

    f32x4 s[2][2];
    #pragma unroll
    for (int h = 0; h < 2; ++h)
        #pragma unroll
        for (int kvh = 0; kvh < 2; ++kvh) {
            s[h][kvh] = (f32x4){0.f, 0.f, 0.f, 0.f};
            s[h][kvh] = __builtin_amdgcn_mfma_f32_16x16x32_bf16(
                            aq[h][0], kb[kvh][0], s[h][kvh], 0, 0, 0);
            s[h][kvh] = __builtin_amdgcn_mfma_f32_16x16x32_bf16(
                            aq[h][1], kb[kvh][1], s[h][kvh], 0, 0, 0);
        }

    #pragma unroll
    for (int h = 0; h < 2; ++h)
        #pragma unroll
        for (int kvh = 0; kvh < 2; ++kvh)
            #pragma unroll
            for (int r = 0; r < 4; ++r) {
                float p = exp2f(fmaf(s[h][kvh][r], C1, C2));
                if constexpr (DIAG) {
                    // tile-local mask (t0 == m0 on the diagonal tile)
                    const bool ok = (kvh * 16 + lr) <= (h * 16 + quad * 4 + r);
                    p = ok ? p : 0.0f;
                }
                pb[(h * 16 + quad * 4 + r) * 40 + kvh * 16 + lr] = (bf16)p;
            }

    bf16x8 ap[2];
    #pragma unroll
    for (int h = 0; h < 2; ++h)
        ap[h] = *(const bf16x8*)&pb[(h * 16 + lr) * 40 + quad * 8];

    #pragma unroll
    for (int h = 0; h < 2; ++h)
        acc_l[h] = __builtin_amdgcn_mfma_f32_16x16x32_bf16(
                        ap[h], ones, acc_l[h], 0, 0, 0);
    #pragma unroll
    for (int c = 0; c < 4; ++c)
        #pragma unroll
        for (int h = 0; h < 2; ++h)
            acc[h][c] = __builtin_amdgcn_mfma_f32_16x16x32_bf16(
                            ap[h], vb[c], acc[h][c], 0, 0, 0);
}

__global__ __launch_bounds__(256, 4) void attn_kernel4(
    const bf16* __restrict__ q_ws, const bf16* __restrict__ k_ws,
    const bf16* __restrict__ v_ws, bf16* __restrict__ z_ws)
{
    __shared__ __align__(16) bf16 Kst[2][32 * 64];   // 2 x 4 KB
    __shared__ __align__(16) bf16 Vst[2][64 * 32];   // 2 x 4 KB
    __shared__ __align__(16) bf16 pbuf[4][32 * 40];  // 10 KB

    const int tid  = threadIdx.x;
    const int w    = tid >> 6;
    const int lane = tid & 63;
    const int quad = lane >> 4;
    const int lr   = lane & 15;

    const int bh = blockIdx.x & 63;          // same-head blocks share XCD
    const int qg = 15 - (blockIdx.x >> 6);   // LPT: heavy groups first
    const int m0 = qg * 128 + w * 32;
    const int lim = 4 * qg + w;              // tile index of this wave's diagonal
    const int ntiles = 4 * qg + 4;

    const size_t base = (size_t)bh * SS * DK;
    const bf16* Kb = k_ws + base;
    const bf16* Vb = v_ws + base;            // [dk][s], stride SS
    bf16* pb = pbuf[w];

    // staging source addresses (per-lane), swizzle-inverted
    const int krow = w * 8 + (lane >> 3);
    const int kcc  = (lane & 7) ^ ((lane >> 3) & 7);
    const bf16* ksrc = Kb + (size_t)krow * DK + kcc * 8;
    const int vrow = w * 16 + (lane >> 2);
    const int vcc  = (lane & 3) ^ ((lane >> 3) & 3);
    const bf16* vsrc = Vb + (size_t)vrow * SS + vcc * 8;

    bf16x8 aq[2][2];
    #pragma unroll
    for (int h = 0; h < 2; ++h)
        #pragma unroll
        for (int kc = 0; kc < 2; ++kc)
            aq[h][kc] = *(const bf16x8*)(q_ws + base
                + (size_t)(m0 + h * 16 + lr) * DK + kc * 32 + quad * 8);

    bf16x8 ones;
    #pragma unroll
    for (int i = 0; i < 8; ++i) ones[i] = (bf16)1.0f;

    f32x4 acc[2][4], acc_l[2];
    #pragma unroll
    for (int h = 0; h < 2; ++h) {
        acc_l[h] = (f32x4){0.f, 0.f, 0.f, 0.f};
        #pragma unroll
        for (int c = 0; c < 4; ++c) acc[h][c] = (f32x4){0.f, 0.f, 0.f, 0.f};
    }

    // stage tile 0
    gl_lds16(ksrc, &Kst[0][w * 512]);
    gl_lds16(vsrc, &Vst[0][w * 512]);
    __syncthreads();

    for (int t = 0; t < ntiles; ++t) {
        if (t + 1 < ntiles) {
            gl_lds16(ksrc + (size_t)(t + 1) * 32 * DK, &Kst[(t + 1) & 1][w * 512]);
            gl_lds16(vsrc + (t + 1) * 32,              &Vst[(t + 1) & 1][w * 512]);
        }
        const bf16* Kc = Kst[t & 1];
        const bf16* Vc = Vst[t & 1];
        if (t < lim)
            attn_tile4<false>(quad, lr, Kc, Vc, pb, aq, ones, acc, acc_l);
        else if (t == lim)
            attn_tile4<true>(quad, lr, Kc, Vc, pb, aq, ones, acc, acc_l);
        __syncthreads();   // drains prefetch (vmcnt) + guards buffer reuse
    }

    // epilogue: l already complete per row in acc_l (every lane has its row sum)
    const int b = bh >> 4, hh = bh & (HH - 1);
    #pragma unroll
    for (int h = 0; h < 2; ++h)
        #pragma unroll
        for (int r = 0; r < 4; ++r) {
            const float inv = 1.0f / acc_l[h][r];
            const int s = m0 + h * 16 + quad * 4 + r;
            #pragma unroll
            for (int c = 0; c < 4; ++c)
                z_ws[((size_t)(b * SS + s)) * DD + hh * DK + c * 16 + lr]
                    = (bf16)(acc[h][c][r] * inv);
        }
}

// ---------------------------------------------------------------------------
extern "C" void kernel_launch(void* const* d_in, const int* in_sizes, int n_in,
                              void* d_out, int out_size, void* d_ws, size_t ws_size,
                              hipStream_t stream)
{
    const float* query = (const float*)d_in[0];
    const float* key_  = (const float*)d_in[1];
    const float* value = (const float*)d_in[2];
    const float* Wq = (const float*)d_in[3];
    const float* bq = (const float*)d_in[4];
    const float* Wk = (const float*)d_in[5];
    const float* bk = (const float*)d_in[6];
    const float* Wv = (const float*)d_in[7];
    const float* bv = (const float*)d_in[8];
    const float* Wp = (const float*)d_in[9];
    const float* bp = (const float*)d_in[10];
    // d_in[11] = causal mask (deterministic tril) — not read.

    const size_t X = (size_t)MTOT * DD;
    const size_t W = (size_t)DD * DD;
    bf16* xq  = (bf16*)d_ws;
    bf16* xk  = xq + X;
    bf16* xv  = xk + X;
    bf16* wqb = xv + X;
    bf16* wkb = wqb + W;
    bf16* wvb = wkb + W;
    bf16* wpb = wvb + W;
    bf16* q_ws = wpb + W;                 // [b,h,s,dk]
    bf16* k_ws = q_ws + X;                // [b,h,s,dk]
    bf16* v_ws = k_ws + X;                // [b,h,dk,s]
    bf16* z_ws = xq;                      // alias: xq dead after Q-GEMM

    conv_kernel<<<dim3(4096, 1, 4), 256, 0, stream>>>(
        query, key_, value, Wq, Wk, Wv, Wp, xq, wqb);

    gemm_qkv<<<dim3(4, 32, 3), 512, 0, stream>>>(
        xq, xk, xv, wqb, wkb, wvb, bq, bk, bv, q_ws, k_ws, v_ws);

    attn_kernel4<<<dim3(1024), 256, 0, stream>>>(q_ws, k_ws, v_ws, z_ws);

    gemm_out<<<dim3(16, 64), 256, 0, stream>>>(z_ws, wpb, bp, (float*)d_out);
}

// Round 3
// 355.788 us; speedup vs baseline: 1.0424x; 1.0351x over previous
//
#include <hip/hip_runtime.h>

typedef __bf16 bf16;
typedef __bf16 bf16x8 __attribute__((ext_vector_type(8)));
typedef float f32x4 __attribute__((ext_vector_type(4)));

#define BB 4
#define SS 2048
#define HH 16
#define DD 1024
#define DK 64
#define MTOT (BB * SS)   // 8192

#define C1 0.18033688f    // 0.125 * log2(e)
#define C2 -11.5415603f   // -8 * log2(e)

// async global->LDS, 16B per lane. LDS dest is WAVE-UNIFORM base; HW scatters
// lane i to base + i*16.
__device__ __forceinline__ void gl_lds16(const bf16* g, bf16* l)
{
    __builtin_amdgcn_global_load_lds(
        (const __attribute__((address_space(1))) unsigned int*)g,
        (__attribute__((address_space(3))) unsigned int*)l, 16, 0, 0);
}

// ---------------------------------------------------------------------------
// fp32 -> bf16 bulk converts, one dispatch. z 0..2: X inputs; z=3: 4 weights.
// ---------------------------------------------------------------------------
__global__ __launch_bounds__(256) void conv_kernel(
    const float* __restrict__ q, const float* __restrict__ k,
    const float* __restrict__ v,
    const float* __restrict__ wq, const float* __restrict__ wk,
    const float* __restrict__ wv, const float* __restrict__ wp,
    bf16* __restrict__ xdst, bf16* __restrict__ wdst)
{
    const float* src; bf16* d; size_t i;
    if (blockIdx.z < 3) {
        src = (blockIdx.z == 0) ? q : (blockIdx.z == 1) ? k : v;
        d = xdst + (size_t)blockIdx.z * ((size_t)MTOT * DD);
        i = ((size_t)blockIdx.x * 256 + threadIdx.x) * 8;
    } else {
        if (blockIdx.x >= 2048) return;
        const int wsel = blockIdx.x >> 9;
        src = (wsel == 0) ? wq : (wsel == 1) ? wk : (wsel == 2) ? wv : wp;
        d = wdst + (size_t)wsel * ((size_t)DD * DD);
        i = ((size_t)(blockIdx.x & 511) * 256 + threadIdx.x) * 8;
    }
    const float4 v0 = *(const float4*)(src + i);
    const float4 v1 = *(const float4*)(src + i + 4);
    bf16x8 r = { (bf16)v0.x, (bf16)v0.y, (bf16)v0.z, (bf16)v0.w,
                 (bf16)v1.x, (bf16)v1.y, (bf16)v1.z, (bf16)v1.w };
    *(bf16x8*)(d + i) = r;
}

// ---------------------------------------------------------------------------
// QKV GEMM, 8-phase 256x256 schedule. BK=64, 512 threads = 8 waves (2M x 4N),
// per-wave C = 128x64. LDS 128 KB (2 dbuf x (A 32KB + B 32KB)).
// sched_barrier(0) fences pin ds_reads BEFORE s_barrier and MFMAs AFTER the
// lgkmcnt(0) (rule #18 / anti-sinking): without them the scheduler may sink
// the 10 live b128 reads past the barrier, serializing LDS vs MFMA pipes.
// ---------------------------------------------------------------------------
template<int KC, int NH>
__device__ __forceinline__ void qphase(
    const bf16* __restrict__ sb, int wm, int wn, int lr, int swz8,
    bf16x8 a[8], f32x4 acc[8][4],
    const bf16* __restrict__ ssrc, bf16* __restrict__ sdst, bool doStage)
{
    if constexpr (NH == 0) {
        #pragma unroll
        for (int i = 0; i < 8; ++i)
            a[i] = *(const bf16x8*)&sb[KC * 8192 + (wm * 128 + i * 16 + lr) * 32 + swz8];
    }
    bf16x8 b0 = *(const bf16x8*)&sb[16384 + KC * 8192 + (wn * 64 + (NH * 2 + 0) * 16 + lr) * 32 + swz8];
    bf16x8 b1 = *(const bf16x8*)&sb[16384 + KC * 8192 + (wn * 64 + (NH * 2 + 1) * 16 + lr) * 32 + swz8];
    __builtin_amdgcn_sched_barrier(0);   // pin reads ABOVE the barrier
    __builtin_amdgcn_s_barrier();
    asm volatile("s_waitcnt lgkmcnt(0)" ::: "memory");
    __builtin_amdgcn_sched_barrier(0);   // rule #18: MFMAs must not hoist past
    __builtin_amdgcn_s_setprio(1);
    #pragma unroll
    for (int i = 0; i < 8; ++i) {
        acc[i][NH * 2 + 0] = __builtin_amdgcn_mfma_f32_16x16x32_bf16(
                                 a[i], b0, acc[i][NH * 2 + 0], 0, 0, 0);
        acc[i][NH * 2 + 1] = __builtin_amdgcn_mfma_f32_16x16x32_bf16(
                                 a[i], b1, acc[i][NH * 2 + 1], 0, 0, 0);
    }
    __builtin_amdgcn_s_setprio(0);
    // stage AFTER the MFMA cluster (post-BAR_A is REQUIRED: distance-2
    // same-parity prefetch overwrites regions of the live buffer; all waves'
    // reads of this region were issued pre-BAR_A).
    if (doStage) {
        gl_lds16(ssrc, sdst);
        gl_lds16(ssrc + (size_t)128 * DD, sdst + 4096);
    }
    __builtin_amdgcn_sched_barrier(0);   // pin stage issues before BAR_B
}

__global__ __launch_bounds__(512, 2) void gemm_qkv(
    const bf16* __restrict__ x0, const bf16* __restrict__ x1,
    const bf16* __restrict__ x2, const bf16* __restrict__ w0,
    const bf16* __restrict__ w1, const bf16* __restrict__ w2,
    const float* __restrict__ bias0, const float* __restrict__ bias1,
    const float* __restrict__ bias2,
    bf16* __restrict__ o0, bf16* __restrict__ o1, bf16* __restrict__ o2)
{
    __shared__ __align__(16) bf16 smem[2 * 32768];   // 128 KB

    const int z = blockIdx.z;
    const bf16* A = (z == 0) ? x0 : (z == 1) ? x1 : x2;
    const bf16* W = (z == 0) ? w0 : (z == 1) ? w1 : w2;
    const float* bias = (z == 0) ? bias0 : (z == 1) ? bias1 : bias2;
    bf16* out = (z == 0) ? o0 : (z == 1) ? o1 : o2;

    const int tid  = threadIdx.x;
    const int w    = tid >> 6;
    const int lane = tid & 63;
    const int quad = lane >> 4;
    const int lr   = lane & 15;
    const int wm   = w >> 2;       // 2 m-waves of 128 rows
    const int wn   = w & 3;        // 4 n-waves of 64 cols

    const int m_base = blockIdx.y * 256;
    const int n_base = blockIdx.x * 256;
    const int swz8 = (quad ^ ((lr >> 1) & 3)) * 8;

    // staging: linear LDS dest; source column pre-swizzled (inverse of read swz)
    const int c0 = ((tid & 3) ^ ((tid >> 3) & 3)) * 8;
    const bf16* srcA = A + (size_t)(m_base + (tid >> 2)) * DD + c0;
    const bf16* srcB = W + (size_t)(n_base + (tid >> 2)) * DD + c0;

    f32x4 acc[8][4];
    #pragma unroll
    for (int i = 0; i < 8; ++i)
        #pragma unroll
        for (int j = 0; j < 4; ++j)
            acc[i][j] = (f32x4){0.f, 0.f, 0.f, 0.f};
    bf16x8 a[8];

    // prologue: stage K-tiles 0 and 1 (8 loads/thread each)
    #pragma unroll
    for (int t = 0; t < 2; ++t) {
        bf16* db = smem + t * 32768;
        #pragma unroll
        for (int kc = 0; kc < 2; ++kc) {
            const bf16* sA = srcA + t * 64 + kc * 32;
            const bf16* sB = srcB + t * 64 + kc * 32;
            gl_lds16(sA,                      db + kc * 8192 + w * 512);
            gl_lds16(sA + (size_t)128 * DD,   db + kc * 8192 + 4096 + w * 512);
            gl_lds16(sB,                      db + 16384 + kc * 8192 + w * 512);
            gl_lds16(sB + (size_t)128 * DD,   db + 16384 + kc * 8192 + 4096 + w * 512);
        }
    }
    asm volatile("s_waitcnt vmcnt(8)" ::: "memory");   // tile 0 landed; tile 1 in flight
    __builtin_amdgcn_s_barrier();

    #pragma unroll 2
    for (int T = 0; T < 16; ++T) {
        const bf16* sb = smem + (T & 1) * 32768;
        bf16* db = smem + (T & 1) * 32768;        // tile T+2 shares parity with T
        const bool st = (T + 2 < 16);
        const int tn = st ? (T + 2) : 0;
        const bf16* sA = srcA + tn * 64;
        const bf16* sB = srcB + tn * 64;

        qphase<0, 0>(sb, wm, wn, lr, swz8, a, acc, sA,      db + w * 512,                 st);
        __builtin_amdgcn_s_barrier();
        qphase<0, 1>(sb, wm, wn, lr, swz8, a, acc, sB,      db + 16384 + w * 512,         st);
        __builtin_amdgcn_s_barrier();
        qphase<1, 0>(sb, wm, wn, lr, swz8, a, acc, sA + 32, db + 8192 + w * 512,          st);
        __builtin_amdgcn_s_barrier();
        qphase<1, 1>(sb, wm, wn, lr, swz8, a, acc, sB + 32, db + 16384 + 8192 + w * 512,  st);
        if (st) asm volatile("s_waitcnt vmcnt(8)" ::: "memory");  // T+1 landed, T+2 flying
        else    asm volatile("s_waitcnt vmcnt(0)" ::: "memory");  // tail drain
        __builtin_amdgcn_s_barrier();
    }

    if (z == 2) {
        // V^T epilogue: per-wave 16x128 transpose buffer (stride 136), 4 rounds.
        bf16* e = smem + w * 2176;
        const int hh = (n_base + wn * 64) >> 6;
        const int mg = m_base + wm * 128;
        const int b  = mg >> 11;
        const int s0 = mg & (SS - 1);
        #pragma unroll
        for (int j = 0; j < 4; ++j) {
            const float bb = bias[n_base + wn * 64 + j * 16 + lr];
            #pragma unroll
            for (int i = 0; i < 8; ++i)
                #pragma unroll
                for (int r = 0; r < 4; ++r)
                    e[lr * 136 + i * 16 + quad * 4 + r] = (bf16)(acc[i][j][r] + bb);
            #pragma unroll
            for (int p = 0; p < 4; ++p) {
                const int nn = p * 4 + quad;
                const int mm = lr * 8;
                const bf16x8 vv = *(const bf16x8*)&e[nn * 136 + mm];
                const int dk = j * 16 + nn;
                *(bf16x8*)(out + ((size_t)(b * HH + hh) * DK + dk) * SS + s0 + mm) = vv;
            }
        }
    } else {
        #pragma unroll
        for (int j = 0; j < 4; ++j) {
            const int n  = n_base + wn * 64 + j * 16 + lr;
            const float bb = bias[n];
            const int hh = n >> 6;
            const int dk = n & (DK - 1);
            #pragma unroll
            for (int i = 0; i < 8; ++i)
                #pragma unroll
                for (int r = 0; r < 4; ++r) {
                    const int m = m_base + wm * 128 + i * 16 + quad * 4 + r;
                    const int bi = m >> 11, s = m & (SS - 1);
                    out[(((size_t)bi * HH + hh) * SS + s) * DK + dk]
                        = (bf16)(acc[i][j][r] + bb);
                }
        }
    }
}

// ---------------------------------------------------------------------------
// Output projection GEMM v2: 256x128 tiles, grid 8x32 = 256 blocks = EXACTLY
// one dispatch wave (no tail). 512 threads = 8 waves (4M x 2N), per-wave
// C = 64x64 (acc[4][4]). BK=64, LDS 96 KB (2 dbuf x (A 32KB + B 16KB)),
// same XOR-chunk swizzle + counted vmcnt(6) + sched_barrier fences.
// 2 phases per K-tile (one per kc half, 16 MFMA each). fp32 output.
// ---------------------------------------------------------------------------
template<int KC>
__device__ __forceinline__ void ophase(
    const bf16* __restrict__ sb, int wm, int wn, int lr, int swz8,
    f32x4 acc[4][4],
    const bf16* __restrict__ sA, const bf16* __restrict__ sB,
    bf16* __restrict__ db, int w, bool doStage)
{
    bf16x8 a[4], b[4];
    #pragma unroll
    for (int i = 0; i < 4; ++i)
        a[i] = *(const bf16x8*)&sb[KC * 8192 + (wm * 64 + i * 16 + lr) * 32 + swz8];
    #pragma unroll
    for (int j = 0; j < 4; ++j)
        b[j] = *(const bf16x8*)&sb[16384 + KC * 4096 + (wn * 64 + j * 16 + lr) * 32 + swz8];
    __builtin_amdgcn_sched_barrier(0);
    __builtin_amdgcn_s_barrier();
    asm volatile("s_waitcnt lgkmcnt(0)" ::: "memory");
    __builtin_amdgcn_sched_barrier(0);
    __builtin_amdgcn_s_setprio(1);
    #pragma unroll
    for (int i = 0; i < 4; ++i)
        #pragma unroll
        for (int j = 0; j < 4; ++j)
            acc[i][j] = __builtin_amdgcn_mfma_f32_16x16x32_bf16(
                            a[i], b[j], acc[i][j], 0, 0, 0);
    __builtin_amdgcn_s_setprio(0);
    if (doStage) {   // stage kc=KC regions of tile T+2 (post-barrier: safe)
        gl_lds16(sA + KC * 32,                    db + KC * 8192 + w * 512);
        gl_lds16(sA + KC * 32 + (size_t)128 * DD, db + KC * 8192 + 4096 + w * 512);
        gl_lds16(sB + KC * 32,                    db + 16384 + KC * 4096 + w * 512);
    }
    __builtin_amdgcn_sched_barrier(0);
}

__global__ __launch_bounds__(512, 2) void gemm_out(
    const bf16* __restrict__ A, const bf16* __restrict__ W,
    const float* __restrict__ bias, float* __restrict__ out)
{
    __shared__ __align__(16) bf16 smem[2 * 24576];   // 96 KB

    const int tid  = threadIdx.x;
    const int w    = tid >> 6;
    const int lane = tid & 63;
    const int quad = lane >> 4;
    const int lr   = lane & 15;
    const int wm   = w >> 1;       // 4 m-waves of 64 rows
    const int wn   = w & 1;        // 2 n-waves of 64 cols

    const int m_base = blockIdx.y * 256;
    const int n_base = blockIdx.x * 128;
    const int swz8 = (quad ^ ((lr >> 1) & 3)) * 8;

    const int c0 = ((tid & 3) ^ ((tid >> 3) & 3)) * 8;
    const bf16* srcA = A + (size_t)(m_base + (tid >> 2)) * DD + c0;
    const bf16* srcB = W + (size_t)(n_base + (tid >> 2)) * DD + c0;

    f32x4 acc[4][4];
    #pragma unroll
    for (int i = 0; i < 4; ++i)
        #pragma unroll
        for (int j = 0; j < 4; ++j)
            acc[i][j] = (f32x4){0.f, 0.f, 0.f, 0.f};

    // prologue: stage K-tiles 0 and 1 (6 loads/thread each)
    #pragma unroll
    for (int t = 0; t < 2; ++t) {
        bf16* db = smem + t * 24576;
        #pragma unroll
        for (int kc = 0; kc < 2; ++kc) {
            const bf16* sA = srcA + t * 64 + kc * 32;
            const bf16* sB = srcB + t * 64 + kc * 32;
            gl_lds16(sA,                      db + kc * 8192 + w * 512);
            gl_lds16(sA + (size_t)128 * DD,   db + kc * 8192 + 4096 + w * 512);
            gl_lds16(sB,                      db + 16384 + kc * 4096 + w * 512);
        }
    }
    asm volatile("s_waitcnt vmcnt(6)" ::: "memory");   // tile 0 landed
    __builtin_amdgcn_s_barrier();

    #pragma unroll 2
    for (int T = 0; T < 16; ++T) {
        const bf16* sb = smem + (T & 1) * 24576;
        bf16* db = smem + (T & 1) * 24576;
        const bool st = (T + 2 < 16);
        const int tn = st ? (T + 2) : 0;
        const bf16* sA = srcA + tn * 64;
        const bf16* sB = srcB + tn * 64;

        ophase<0>(sb, wm, wn, lr, swz8, acc, sA, sB, db, w, st);
        __builtin_amdgcn_s_barrier();
        ophase<1>(sb, wm, wn, lr, swz8, acc, sA, sB, db, w, st);
        if (st) asm volatile("s_waitcnt vmcnt(6)" ::: "memory");  // T+1 landed
        else    asm volatile("s_waitcnt vmcnt(0)" ::: "memory");  // tail drain
        __builtin_amdgcn_s_barrier();
    }

    #pragma unroll
    for (int j = 0; j < 4; ++j) {
        const int n = n_base + wn * 64 + j * 16 + lr;
        const float bb = bias[n];
        #pragma unroll
        for (int i = 0; i < 4; ++i)
            #pragma unroll
            for (int r = 0; r < 4; ++r) {
                const int m = m_base + wm * 64 + i * 16 + quad * 4 + r;
                out[(size_t)m * DD + n] = acc[i][j][r] + bb;
            }
    }
}

// ---------------------------------------------------------------------------
// MFMA flash attention v4: 4-wave blocks; wave w owns 32 Q rows
// (m0 = qg*128 + w*32); K/V 32-wide tiles staged ONCE per block into
// double-buffered LDS (XOR-swizzled 16B chunks -> uniform-bank b128 reads).
// Fixed-max softmax p = exp2(s*C1 + C2). Row-sum l via MFMA ones-fragment.
// ---------------------------------------------------------------------------
template <bool DIAG>
__device__ __forceinline__ void attn_tile4(
    int quad, int lr, const bf16* __restrict__ Kc, const bf16* __restrict__ Vc,
    bf16* __restrict__ pb, const bf16x8 aq[2][2], const bf16x8& ones,
    f32x4 acc[2][4], f32x4 acc_l[2])
{
    // K frags: logical (row=kvh*16+lr, cc=kc*4+quad), phys chunk row*8 + (cc^(row&7))
    bf16x8 kb[2][2];
    #pragma unroll
    for (int kvh = 0; kvh < 2; ++kvh)
        #pragma unroll
        for (int kc = 0; kc < 2; ++kc)
            kb[kvh][kc] = *(const bf16x8*)&Kc[
                ((kvh * 16 + lr) * 8 + ((kc * 4 + quad) ^ (lr & 7))) * 8];
    // V frags: logical (row=c*16+lr, cc=quad), phys chunk row*4 + (cc^((row>>1)&3))
    bf16x8 vb[4];
    #pragma unroll
    for (int c = 0; c < 4; ++c)
        vb[c] = *(const bf16x8*)&Vc[
            ((c * 16 + lr) * 4 + (quad ^ ((lr >> 1) & 3))) * 8];

    f32x4 s[2][2];
    #pragma unroll
    for (int h = 0; h < 2; ++h)
        #pragma unroll
        for (int kvh = 0; kvh < 2; ++kvh) {
            s[h][kvh] = (f32x4){0.f, 0.f, 0.f, 0.f};
            s[h][kvh] = __builtin_amdgcn_mfma_f32_16x16x32_bf16(
                            aq[h][0], kb[kvh][0], s[h][kvh], 0, 0, 0);
            s[h][kvh] = __builtin_amdgcn_mfma_f32_16x16x32_bf16(
                            aq[h][1], kb[kvh][1], s[h][kvh], 0, 0, 0);
        }

    #pragma unroll
    for (int h = 0; h < 2; ++h)
        #pragma unroll
        for (int kvh = 0; kvh < 2; ++kvh)
            #pragma unroll
            for (int r = 0; r < 4; ++r) {
                float p = exp2f(fmaf(s[h][kvh][r], C1, C2));
                if constexpr (DIAG) {
                    // tile-local mask (t0 == m0 on the diagonal tile)
                    const bool ok = (kvh * 16 + lr) <= (h * 16 + quad * 4 + r);
                    p = ok ? p : 0.0f;
                }
                pb[(h * 16 + quad * 4 + r) * 40 + kvh * 16 + lr] = (bf16)p;
            }

    bf16x8 ap[2];
    #pragma unroll
    for (int h = 0; h < 2; ++h)
        ap[h] = *(const bf16x8*)&pb[(h * 16 + lr) * 40 + quad * 8];

    #pragma unroll
    for (int h = 0; h < 2; ++h)
        acc_l[h] = __builtin_amdgcn_mfma_f32_16x16x32_bf16(
                        ap[h], ones, acc_l[h], 0, 0, 0);
    #pragma unroll
    for (int c = 0; c < 4; ++c)
        #pragma unroll
        for (int h = 0; h < 2; ++h)
            acc[h][c] = __builtin_amdgcn_mfma_f32_16x16x32_bf16(
                            ap[h], vb[c], acc[h][c], 0, 0, 0);
}

__global__ __launch_bounds__(256, 4) void attn_kernel4(
    const bf16* __restrict__ q_ws, const bf16* __restrict__ k_ws,
    const bf16* __restrict__ v_ws, bf16* __restrict__ z_ws)
{
    __shared__ __align__(16) bf16 Kst[2][32 * 64];   // 2 x 4 KB
    __shared__ __align__(16) bf16 Vst[2][64 * 32];   // 2 x 4 KB
    __shared__ __align__(16) bf16 pbuf[4][32 * 40];  // 10 KB

    const int tid  = threadIdx.x;
    const int w    = tid >> 6;
    const int lane = tid & 63;
    const int quad = lane >> 4;
    const int lr   = lane & 15;

    const int bh = blockIdx.x & 63;          // same-head blocks share XCD
    const int qg = 15 - (blockIdx.x >> 6);   // LPT: heavy groups first
    const int m0 = qg * 128 + w * 32;
    const int lim = 4 * qg + w;              // tile index of this wave's diagonal
    const int ntiles = 4 * qg + 4;

    const size_t base = (size_t)bh * SS * DK;
    const bf16* Kb = k_ws + base;
    const bf16* Vb = v_ws + base;            // [dk][s], stride SS
    bf16* pb = pbuf[w];

    // staging source addresses (per-lane), swizzle-inverted
    const int krow = w * 8 + (lane >> 3);
    const int kcc  = (lane & 7) ^ ((lane >> 3) & 7);
    const bf16* ksrc = Kb + (size_t)krow * DK + kcc * 8;
    const int vrow = w * 16 + (lane >> 2);
    const int vcc  = (lane & 3) ^ ((lane >> 3) & 3);
    const bf16* vsrc = Vb + (size_t)vrow * SS + vcc * 8;

    bf16x8 aq[2][2];
    #pragma unroll
    for (int h = 0; h < 2; ++h)
        #pragma unroll
        for (int kc = 0; kc < 2; ++kc)
            aq[h][kc] = *(const bf16x8*)(q_ws + base
                + (size_t)(m0 + h * 16 + lr) * DK + kc * 32 + quad * 8);

    bf16x8 ones;
    #pragma unroll
    for (int i = 0; i < 8; ++i) ones[i] = (bf16)1.0f;

    f32x4 acc[2][4], acc_l[2];
    #pragma unroll
    for (int h = 0; h < 2; ++h) {
        acc_l[h] = (f32x4){0.f, 0.f, 0.f, 0.f};
        #pragma unroll
        for (int c = 0; c < 4; ++c) acc[h][c] = (f32x4){0.f, 0.f, 0.f, 0.f};
    }

    // stage tile 0
    gl_lds16(ksrc, &Kst[0][w * 512]);
    gl_lds16(vsrc, &Vst[0][w * 512]);
    __syncthreads();

    for (int t = 0; t < ntiles; ++t) {
        if (t + 1 < ntiles) {
            gl_lds16(ksrc + (size_t)(t + 1) * 32 * DK, &Kst[(t + 1) & 1][w * 512]);
            gl_lds16(vsrc + (t + 1) * 32,              &Vst[(t + 1) & 1][w * 512]);
        }
        const bf16* Kc = Kst[t & 1];
        const bf16* Vc = Vst[t & 1];
        if (t < lim)
            attn_tile4<false>(quad, lr, Kc, Vc, pb, aq, ones, acc, acc_l);
        else if (t == lim)
            attn_tile4<true>(quad, lr, Kc, Vc, pb, aq, ones, acc, acc_l);
        __syncthreads();   // drains prefetch (vmcnt) + guards buffer reuse
    }

    // epilogue: l already complete per row in acc_l (every lane has its row sum)
    const int b = bh >> 4, hh = bh & (HH - 1);
    #pragma unroll
    for (int h = 0; h < 2; ++h)
        #pragma unroll
        for (int r = 0; r < 4; ++r) {
            const float inv = 1.0f / acc_l[h][r];
            const int s = m0 + h * 16 + quad * 4 + r;
            #pragma unroll
            for (int c = 0; c < 4; ++c)
                z_ws[((size_t)(b * SS + s)) * DD + hh * DK + c * 16 + lr]
                    = (bf16)(acc[h][c][r] * inv);
        }
}

// ---------------------------------------------------------------------------
extern "C" void kernel_launch(void* const* d_in, const int* in_sizes, int n_in,
                              void* d_out, int out_size, void* d_ws, size_t ws_size,
                              hipStream_t stream)
{
    const float* query = (const float*)d_in[0];
    const float* key_  = (const float*)d_in[1];
    const float* value = (const float*)d_in[2];
    const float* Wq = (const float*)d_in[3];
    const float* bq = (const float*)d_in[4];
    const float* Wk = (const float*)d_in[5];
    const float* bk = (const float*)d_in[6];
    const float* Wv = (const float*)d_in[7];
    const float* bv = (const float*)d_in[8];
    const float* Wp = (const float*)d_in[9];
    const float* bp = (const float*)d_in[10];
    // d_in[11] = causal mask (deterministic tril) — not read.

    const size_t X = (size_t)MTOT * DD;
    const size_t W = (size_t)DD * DD;
    bf16* xq  = (bf16*)d_ws;
    bf16* xk  = xq + X;
    bf16* xv  = xk + X;
    bf16* wqb = xv + X;
    bf16* wkb = wqb + W;
    bf16* wvb = wkb + W;
    bf16* wpb = wvb + W;
    bf16* q_ws = wpb + W;                 // [b,h,s,dk]
    bf16* k_ws = q_ws + X;                // [b,h,s,dk]
    bf16* v_ws = k_ws + X;                // [b,h,dk,s]
    bf16* z_ws = xq;                      // alias: xq dead after Q-GEMM

    conv_kernel<<<dim3(4096, 1, 4), 256, 0, stream>>>(
        query, key_, value, Wq, Wk, Wv, Wp, xq, wqb);

    gemm_qkv<<<dim3(4, 32, 3), 512, 0, stream>>>(
        xq, xk, xv, wqb, wkb, wvb, bq, bk, bv, q_ws, k_ws, v_ws);

    attn_kernel4<<<dim3(1024), 256, 0, stream>>>(q_ws, k_ws, v_ws, z_ws);

    gemm_out<<<dim3(8, 32), 512, 0, stream>>>(z_ws, wpb, bp, (float*)d_out);
}